// Round 11
// baseline (332.944 us; speedup 1.0000x reference)
//
#include <hip/hip_runtime.h>
#include <hip/hip_fp16.h>

#define N_NODES 50000
#define N_EDGES 800000
#define IN_CH 64
#define HID 128

typedef __attribute__((ext_vector_type(8))) short bf16x8;
typedef __attribute__((ext_vector_type(4))) float f32x4;

// Split-bf16 packing: v ~= hi + lo, both bf16 (RNE). Packed as (hi<<16)|lo.
__device__ __forceinline__ unsigned pack_split(float v) {
    unsigned u = __float_as_uint(v);
    unsigned hi = (u + 0x7fffu + ((u >> 16) & 1u)) & 0xffff0000u;
    float r = v - __uint_as_float(hi);
    unsigned ur = __float_as_uint(r);
    unsigned lo = ((ur + 0x7fffu + ((ur >> 16) & 1u)) >> 16) & 0xffffu;
    return hi | lo;
}

__device__ __forceinline__ float unpack_f(unsigned u) {
    return __uint_as_float(u & 0xffff0000u) + __uint_as_float(u << 16);
}

// ---------------- CSR build ----------------

// 4 edges per thread, int4 index load.
__global__ __launch_bounds__(256) void count_edges(const int* __restrict__ dst,
                                                   int* __restrict__ counts, int e) {
    int i4 = (blockIdx.x * blockDim.x + threadIdx.x) * 4;
    if (i4 + 3 < e) {
        int4 d = *(const int4*)&dst[i4];
        atomicAdd(&counts[d.x], 1);
        atomicAdd(&counts[d.y], 1);
        atomicAdd(&counts[d.z], 1);
        atomicAdd(&counts[d.w], 1);
    } else {
        for (int i = i4; i < e; ++i) atomicAdd(&counts[dst[i]], 1);
    }
}

__global__ __launch_bounds__(256) void scan_block(const int* __restrict__ counts,
                                                  int* __restrict__ partial,
                                                  int* __restrict__ block_sums, int n) {
    __shared__ int wsum[4];
    int base = (int)blockIdx.x * 1024 + (int)threadIdx.x * 4;
    int4 v = make_int4(0, 0, 0, 0);
    if (base + 3 < n) {
        v = *(const int4*)&counts[base];
    } else {
        if (base + 0 < n) v.x = counts[base + 0];
        if (base + 1 < n) v.y = counts[base + 1];
        if (base + 2 < n) v.z = counts[base + 2];
        if (base + 3 < n) v.w = counts[base + 3];
    }
    v.y += v.x; v.z += v.y; v.w += v.z;
    int tot = v.w;
    int lane = (int)threadIdx.x & 63;
    int wid = (int)threadIdx.x >> 6;
    int s = tot;
#pragma unroll
    for (int off = 1; off < 64; off <<= 1) {
        int t = __shfl_up(s, off);
        if (lane >= off) s += t;
    }
    if (lane == 63) wsum[wid] = s;
    __syncthreads();
    int woff = 0;
#pragma unroll
    for (int w = 0; w < 4; ++w)
        if (w < wid) woff += wsum[w];
    int excl = woff + s - tot;
    v.x += excl; v.y += excl; v.z += excl; v.w += excl;
    if (base + 3 < n) {
        *(int4*)&partial[base] = v;
    } else {
        if (base + 0 < n) partial[base + 0] = v.x;
        if (base + 1 < n) partial[base + 1] = v.y;
        if (base + 2 < n) partial[base + 2] = v.z;
        if (base + 3 < n) partial[base + 3] = v.w;
    }
    if (threadIdx.x == 255) block_sums[blockIdx.x] = woff + s;
}

__global__ __launch_bounds__(256) void finalize_rowptr(const int* __restrict__ partial,
                                                       const int* __restrict__ block_sums,
                                                       int* __restrict__ row_ptr,
                                                       int n, int nblocks) {
    __shared__ int s_off;
    if (threadIdx.x < 64) {
        int lane = (int)threadIdx.x;
        int v = (lane < (int)blockIdx.x && lane < nblocks) ? block_sums[lane] : 0;
#pragma unroll
        for (int off = 32; off > 0; off >>= 1) v += __shfl_down(v, off);
        if (lane == 0) s_off = v;
    }
    __syncthreads();
    int off = s_off;
    int base = (int)blockIdx.x * 1024 + (int)threadIdx.x * 4;
#pragma unroll
    for (int q = 0; q < 4; ++q) {
        int i = base + q;
        if (i < n) row_ptr[i + 1] = partial[i] + off;
    }
    if (blockIdx.x == 0 && threadIdx.x == 0) row_ptr[0] = 0;
}

// Scatter with non-temporal 8B stores: bypass L2 write-allocate so the
// random single-line dirtying (64B writeback per edge) is avoided.
__global__ __launch_bounds__(256) void fill_csr(
    const int* __restrict__ src, const int* __restrict__ dst,
    const float* __restrict__ w, const int* __restrict__ row_ptr,
    int* __restrict__ cursor, int2* __restrict__ csr_pack, int e) {
    int i = blockIdx.x * blockDim.x + threadIdx.x;
    if (i >= e) return;
    int d = dst[i];
    int p = row_ptr[d] + atomicAdd(&cursor[d], 1);
    unsigned long long v =
        ((unsigned long long)(unsigned)__float_as_uint(w[i]) << 32) | (unsigned)src[i];
    __builtin_nontemporal_store(v, (unsigned long long*)&csr_pack[p]);
}

// ---------------- Fused input/weight split-bf16 prep -------------------------
// All threads: pack x to split-bf16 (GEMM A operand) and fp16 (gather source).
// Threads [0, 81920): also pack one weight element.

__global__ __launch_bounds__(256) void pack_all(
    const float* __restrict__ x, unsigned* __restrict__ xp, __half* __restrict__ xh, int nx,
    const float* __restrict__ w_rel0, const float* __restrict__ w_root0,
    const float* __restrict__ w_ro0, const float* __restrict__ w_rel1,
    const float* __restrict__ w_root1, const float* __restrict__ w_ro1,
    unsigned short* __restrict__ hi, unsigned short* __restrict__ lo) {
    int i = blockIdx.x * blockDim.x + threadIdx.x;
    if (i < nx) {
        float v = x[i];
        xp[i] = pack_split(v);
        xh[i] = __float2half(v);
    }
    if (i < 81920) {
        const float* src;
        int li;
        if (i < 8192) { src = w_rel0; li = i; }
        else if (i < 16384) { src = w_root0; li = i - 8192; }
        else if (i < 32768) { src = w_ro0; li = i - 16384; }
        else if (i < 49152) { src = w_rel1; li = i - 32768; }
        else if (i < 65536) { src = w_root1; li = i - 49152; }
        else { src = w_ro1; li = i - 65536; }
        unsigned p = pack_split(src[li]);
        hi[i] = (unsigned short)(p >> 16);
        lo[i] = (unsigned short)(p & 0xffffu);
    }
}

// ---------------- Aggregation: one wave per node, tiered unroll -------------

// fp16 gather, 1 channel per lane (2B loads), 128B per node row.
template <int T>
__device__ __forceinline__ void agg_tier64h(const __half* __restrict__ h,
                                            const int2* __restrict__ cp,
                                            int& e, int end, int lane, float& acc) {
    for (; e + T <= end; e += T) {
        int2 p[T];
        __half v[T];
#pragma unroll
        for (int q = 0; q < T; ++q) p[q] = cp[e + q];
#pragma unroll
        for (int q = 0; q < T; ++q) v[q] = h[p[q].x * 64 + lane];
#pragma unroll
        for (int q = 0; q < T; ++q) acc += __int_as_float(p[q].y) * __half2float(v[q]);
    }
}

// fp16 gather: one half2 (4B) per lane covers 2 channels; 256B per node row.
template <int T>
__device__ __forceinline__ void agg_tier128h(const unsigned* __restrict__ h2,
                                             const int2* __restrict__ cp,
                                             int& e, int end, int lane,
                                             float& ax, float& ay) {
    for (; e + T <= end; e += T) {
        int2 p[T];
        unsigned v[T];
#pragma unroll
        for (int q = 0; q < T; ++q) p[q] = cp[e + q];
#pragma unroll
        for (int q = 0; q < T; ++q) v[q] = h2[p[q].x * 64 + lane];
#pragma unroll
        for (int q = 0; q < T; ++q) {
            float wv = __int_as_float(p[q].y);
            float2 f = __half22float2(*(const __half2*)&v[q]);
            ax += wv * f.x;
            ay += wv * f.y;
        }
    }
}

// layer-0: fp16 gather of x (64 ch), packed split-bf16 out.
__global__ void aggregate64(const __half* __restrict__ h, const int* __restrict__ row_ptr,
                            const int2* __restrict__ csr_pack,
                            unsigned* __restrict__ agg, int n) {
    int lane = threadIdx.x & 63;
    int node = (int)((blockIdx.x * blockDim.x + threadIdx.x) >> 6);
    if (node >= n) return;
    node = __builtin_amdgcn_readfirstlane(node);
    int beg = row_ptr[node], end = row_ptr[node + 1];
    float inv = 1.0f / fmaxf((float)(end - beg), 1.0f);
    float acc = 0.0f;
    int e = beg;
    agg_tier64h<16>(h, csr_pack, e, end, lane, acc);
    agg_tier64h<8>(h, csr_pack, e, end, lane, acc);
    agg_tier64h<4>(h, csr_pack, e, end, lane, acc);
    agg_tier64h<1>(h, csr_pack, e, end, lane, acc);
    agg[node * 64 + lane] = pack_split(acc * inv);
}

// layer-1: fp16 gather of h2 (128 ch), packed split-bf16 out.
__global__ void aggregate128(const unsigned* __restrict__ h2h, const int* __restrict__ row_ptr,
                             const int2* __restrict__ csr_pack,
                             unsigned* __restrict__ agg, int n) {
    int lane = threadIdx.x & 63;
    int node = (int)((blockIdx.x * blockDim.x + threadIdx.x) >> 6);
    if (node >= n) return;
    node = __builtin_amdgcn_readfirstlane(node);
    int beg = row_ptr[node], end = row_ptr[node + 1];
    float inv = 1.0f / fmaxf((float)(end - beg), 1.0f);
    float ax = 0.0f, ay = 0.0f;
    int e = beg;
    agg_tier128h<16>(h2h, csr_pack, e, end, lane, ax, ay);
    agg_tier128h<8>(h2h, csr_pack, e, end, lane, ax, ay);
    agg_tier128h<4>(h2h, csr_pack, e, end, lane, ax, ay);
    agg_tier128h<1>(h2h, csr_pack, e, end, lane, ax, ay);
    uint2 o;
    o.x = pack_split(ax * inv);
    o.y = pack_split(ay * inv);
    ((uint2*)agg)[node * 64 + lane] = o;
}

// ---------------- MFMA split-bf16 GEMM, W held in registers ------------------
// EMIT: 0 = packed out; 1 = packed + fp16 out; 2 = fused prediction head.

template <int K, int NMAT, bool RELU, int EMIT>
__global__ __launch_bounds__(256, 2) void gemm_mfma(
    const unsigned* __restrict__ A0,
    const unsigned short* __restrict__ W0Hi, const unsigned short* __restrict__ W0Lo,
    const unsigned* __restrict__ A1,
    const unsigned short* __restrict__ W1Hi, const unsigned short* __restrict__ W1Lo,
    const float* __restrict__ bias, void* __restrict__ Yv, __half* __restrict__ Yh,
    const float* __restrict__ pred_w, const float* __restrict__ pred_b,
    float* __restrict__ pred_out, int n) {
    constexpr int KS = K / 32;
    const int lane = (int)threadIdx.x & 63;
    const int wv = (int)threadIdx.x >> 6;
    const int col = lane & 15;
    const int quad = lane >> 4;

    bf16x8 wh[NMAT][2][KS], wl[NMAT][2][KS];
#pragma unroll
    for (int m = 0; m < NMAT; ++m) {
        const unsigned short* Whi = m ? W1Hi : W0Hi;
        const unsigned short* Wlo = m ? W1Lo : W0Lo;
#pragma unroll
        for (int tt = 0; tt < 2; ++tt) {
            const int j = (2 * wv + tt) * 16 + col;
#pragma unroll
            for (int ks = 0; ks < KS; ++ks) {
                const size_t wo = (size_t)j * K + ks * 32 + quad * 8;
                wh[m][tt][ks] = *(const bf16x8*)&Whi[wo];
                wl[m][tt][ks] = *(const bf16x8*)&Wlo[wo];
            }
        }
    }

    float bb[2], wpv[2];
#pragma unroll
    for (int tt = 0; tt < 2; ++tt) {
        bb[tt] = bias[(2 * wv + tt) * 16 + col];
        if constexpr (EMIT == 2) wpv[tt] = pred_w[(2 * wv + tt) * 16 + col];
    }

    const int ngroups = (n + 15) >> 4;
    for (int g = (int)blockIdx.x; g < ngroups; g += (int)gridDim.x) {
        const int m0 = g * 16;
        int arow = m0 + col;
        if (arow >= n) arow = n - 1;

        f32x4 acc[2];
#pragma unroll
        for (int tt = 0; tt < 2; ++tt) acc[tt] = (f32x4){0.f, 0.f, 0.f, 0.f};

#pragma unroll
        for (int m = 0; m < NMAT; ++m) {
            const unsigned* Ap = m ? A1 : A0;
#pragma unroll
            for (int ks = 0; ks < KS; ++ks) {
                const unsigned* ap = &Ap[(size_t)arow * K + ks * 32 + quad * 8];
                uint4 q0 = *(const uint4*)ap;
                uint4 q1 = *(const uint4*)(ap + 4);
                bf16x8 ahi, alo;
                ahi[0] = (short)(q0.x >> 16); alo[0] = (short)(q0.x & 0xffffu);
                ahi[1] = (short)(q0.y >> 16); alo[1] = (short)(q0.y & 0xffffu);
                ahi[2] = (short)(q0.z >> 16); alo[2] = (short)(q0.z & 0xffffu);
                ahi[3] = (short)(q0.w >> 16); alo[3] = (short)(q0.w & 0xffffu);
                ahi[4] = (short)(q1.x >> 16); alo[4] = (short)(q1.x & 0xffffu);
                ahi[5] = (short)(q1.y >> 16); alo[5] = (short)(q1.y & 0xffffu);
                ahi[6] = (short)(q1.z >> 16); alo[6] = (short)(q1.z & 0xffffu);
                ahi[7] = (short)(q1.w >> 16); alo[7] = (short)(q1.w & 0xffffu);
#pragma unroll
                for (int tt = 0; tt < 2; ++tt) {
                    acc[tt] = __builtin_amdgcn_mfma_f32_16x16x32_bf16(ahi, wh[m][tt][ks], acc[tt], 0, 0, 0);
                    acc[tt] = __builtin_amdgcn_mfma_f32_16x16x32_bf16(ahi, wl[m][tt][ks], acc[tt], 0, 0, 0);
                    acc[tt] = __builtin_amdgcn_mfma_f32_16x16x32_bf16(alo, wh[m][tt][ks], acc[tt], 0, 0, 0);
                }
            }
        }

        float yv[2][4];
#pragma unroll
        for (int tt = 0; tt < 2; ++tt)
#pragma unroll
            for (int r = 0; r < 4; ++r) {
                float y = acc[tt][r] + bb[tt];
                if (RELU) y = fmaxf(y, 0.f);
                yv[tt][r] = y;
            }

        if constexpr (EMIT != 2) {
#pragma unroll
            for (int tt = 0; tt < 2; ++tt) {
                const int j = (2 * wv + tt) * 16 + col;
#pragma unroll
                for (int r = 0; r < 4; ++r) {
                    int node = m0 + quad * 4 + r;
                    if (node >= n) continue;
                    ((unsigned*)Yv)[(size_t)node * 128 + j] = pack_split(yv[tt][r]);
                    if constexpr (EMIT == 1)
                        Yh[(size_t)node * 128 + j] = __float2half(yv[tt][r]);
                }
            }
        } else {
            __shared__ float pp[4][16];
            float pr[4];
#pragma unroll
            for (int r = 0; r < 4; ++r) pr[r] = yv[0][r] * wpv[0] + yv[1][r] * wpv[1];
#pragma unroll
            for (int off = 8; off > 0; off >>= 1)
#pragma unroll
                for (int r = 0; r < 4; ++r) pr[r] += __shfl_down(pr[r], off);
            if (col == 0) {
#pragma unroll
                for (int r = 0; r < 4; ++r) pp[wv][quad * 4 + r] = pr[r];
            }
            __syncthreads();
            if (wv == 0 && lane < 16) {
                int node = m0 + lane;
                if (node < n)
                    pred_out[node] = pp[0][lane] + pp[1][lane] + pp[2][lane] + pp[3][lane] + pred_b[0];
            }
            __syncthreads();
        }
    }
}

// ---------------- Launch ----------------

extern "C" void kernel_launch(void* const* d_in, const int* in_sizes, int n_in,
                              void* d_out, int out_size, void* d_ws, size_t ws_size,
                              hipStream_t stream) {
    const float* x = (const float*)d_in[0];
    const int* edge_index = (const int*)d_in[1];
    const float* edge_w = (const float*)d_in[2];
    const float* W_rel0 = (const float*)d_in[3];
    const float* b_rel0 = (const float*)d_in[4];
    const float* W_root0 = (const float*)d_in[5];
    const float* W_ro0 = (const float*)d_in[6];
    const float* b_ro0 = (const float*)d_in[7];
    const float* W_rel1 = (const float*)d_in[8];
    const float* b_rel1 = (const float*)d_in[9];
    const float* W_root1 = (const float*)d_in[10];
    const float* W_ro1 = (const float*)d_in[11];
    const float* b_ro1 = (const float*)d_in[12];
    const float* W_prd = (const float*)d_in[13];
    const float* b_prd = (const float*)d_in[14];
    float* out = (float*)d_out;

    const int* e_src = edge_index;
    const int* e_dst = edge_index + N_EDGES;

    char* ws = (char*)d_ws;
    size_t off = 0;
    auto alloc = [&](size_t bytes) {
        char* p = ws + off;
        off += (bytes + 255) & ~(size_t)255;
        return p;
    };
    int* counts = (int*)alloc(N_NODES * 4);   // adjacent to cursor (one memset)
    int* cursor = (int*)alloc(N_NODES * 4);
    int* row_ptr = (int*)alloc((N_NODES + 1) * 4);
    int* partial = (int*)alloc(N_NODES * 4);
    int* block_sums = (int*)alloc(64 * 4);
    int2* csr_pack = (int2*)alloc((size_t)N_EDGES * 8);
    unsigned short* WHI = (unsigned short*)alloc(81920 * 2);
    unsigned short* WLO = (unsigned short*)alloc(81920 * 2);
    unsigned* xp = (unsigned*)alloc((size_t)N_NODES * 64 * 4);
    __half* xh = (__half*)alloc((size_t)N_NODES * 64 * 2);
    unsigned* AGGp = (unsigned*)alloc((size_t)N_NODES * 128 * 4);
    unsigned* B1p = (unsigned*)alloc((size_t)N_NODES * 128 * 4);
    unsigned* B2p = (unsigned*)alloc((size_t)N_NODES * 128 * 4);
    __half* H2h = (__half*)alloc((size_t)N_NODES * 128 * 2);

    const size_t CA = (N_NODES * 4 + 255) & ~(size_t)255;
    hipMemsetAsync(counts, 0, 2 * CA, stream);

    const int SB = (N_NODES + 1023) / 1024;
    count_edges<<<(N_EDGES / 4 + 255) / 256, 256, 0, stream>>>(e_dst, counts, N_EDGES);
    scan_block<<<SB, 256, 0, stream>>>(counts, partial, block_sums, N_NODES);
    finalize_rowptr<<<SB, 256, 0, stream>>>(partial, block_sums, row_ptr, N_NODES, SB);
    fill_csr<<<(N_EDGES + 255) / 256, 256, 0, stream>>>(
        e_src, e_dst, edge_w, row_ptr, cursor, csr_pack, N_EDGES);

    pack_all<<<(N_NODES * 64 + 255) / 256, 256, 0, stream>>>(
        x, xp, xh, N_NODES * 64, W_rel0, W_root0, W_ro0, W_rel1, W_root1, W_ro1, WHI, WLO);

    const int AGGB = (N_NODES * 64 + 255) / 256;  // wave per node
    const int GGRID = 512;                        // gemm blocks (grid-stride)

    // layer 0
    aggregate64<<<AGGB, 256, 0, stream>>>(xh, row_ptr, csr_pack, AGGp, N_NODES);
    gemm_mfma<64, 2, true, 0><<<GGRID, 256, 0, stream>>>(
        AGGp, WHI + 0, WLO + 0, xp, WHI + 8192, WLO + 8192, b_rel0,
        B1p, nullptr, nullptr, nullptr, nullptr, N_NODES);
    gemm_mfma<128, 1, true, 1><<<GGRID, 256, 0, stream>>>(
        B1p, WHI + 16384, WLO + 16384, nullptr, nullptr, nullptr, b_ro0,
        B2p, H2h, nullptr, nullptr, nullptr, N_NODES);
    // layer 1
    aggregate128<<<AGGB, 256, 0, stream>>>((const unsigned*)H2h, row_ptr, csr_pack, AGGp, N_NODES);
    gemm_mfma<128, 2, true, 0><<<GGRID, 256, 0, stream>>>(
        AGGp, WHI + 32768, WLO + 32768, B2p, WHI + 49152, WLO + 49152, b_rel1,
        B1p, nullptr, nullptr, nullptr, nullptr, N_NODES);
    // final layer + fused prediction head (h4 never materialized)
    gemm_mfma<128, 1, true, 2><<<GGRID, 256, 0, stream>>>(
        B1p, WHI + 65536, WLO + 65536, nullptr, nullptr, nullptr, b_ro1,
        nullptr, nullptr, W_prd, b_prd, out, N_NODES);
}

// Round 12
// 315.091 us; speedup vs baseline: 1.0567x; 1.0567x over previous
//
#include <hip/hip_runtime.h>
#include <hip/hip_fp16.h>

#define N_NODES 50000
#define N_EDGES 800000
#define IN_CH 64
#define HID 128

typedef __attribute__((ext_vector_type(8))) short bf16x8;
typedef __attribute__((ext_vector_type(4))) float f32x4;

// Split-bf16 packing: v ~= hi + lo, both bf16 (RNE). Packed as (hi<<16)|lo.
__device__ __forceinline__ unsigned pack_split(float v) {
    unsigned u = __float_as_uint(v);
    unsigned hi = (u + 0x7fffu + ((u >> 16) & 1u)) & 0xffff0000u;
    float r = v - __uint_as_float(hi);
    unsigned ur = __float_as_uint(r);
    unsigned lo = ((ur + 0x7fffu + ((ur >> 16) & 1u)) >> 16) & 0xffffu;
    return hi | lo;
}

__device__ __forceinline__ float unpack_f(unsigned u) {
    return __uint_as_float(u & 0xffff0000u) + __uint_as_float(u << 16);
}

// ---------------- CSR build ----------------

// Fused count + rank: rank[i] = fetch-add on counts[dst[i]] — the unique
// within-segment slot later used by fill_csr (no cursor atomic needed there).
__global__ __launch_bounds__(256) void count_edges(const int* __restrict__ dst,
                                                   int* __restrict__ counts,
                                                   int* __restrict__ rank, int e) {
    int i4 = (blockIdx.x * blockDim.x + threadIdx.x) * 4;
    if (i4 + 3 < e) {
        int4 d = *(const int4*)&dst[i4];
        int4 r;
        r.x = atomicAdd(&counts[d.x], 1);
        r.y = atomicAdd(&counts[d.y], 1);
        r.z = atomicAdd(&counts[d.z], 1);
        r.w = atomicAdd(&counts[d.w], 1);
        *(int4*)&rank[i4] = r;
    } else {
        for (int i = i4; i < e; ++i) rank[i] = atomicAdd(&counts[dst[i]], 1);
    }
}

__global__ __launch_bounds__(256) void scan_block(const int* __restrict__ counts,
                                                  int* __restrict__ partial,
                                                  int* __restrict__ block_sums, int n) {
    __shared__ int wsum[4];
    int base = (int)blockIdx.x * 1024 + (int)threadIdx.x * 4;
    int4 v = make_int4(0, 0, 0, 0);
    if (base + 3 < n) {
        v = *(const int4*)&counts[base];
    } else {
        if (base + 0 < n) v.x = counts[base + 0];
        if (base + 1 < n) v.y = counts[base + 1];
        if (base + 2 < n) v.z = counts[base + 2];
        if (base + 3 < n) v.w = counts[base + 3];
    }
    v.y += v.x; v.z += v.y; v.w += v.z;
    int tot = v.w;
    int lane = (int)threadIdx.x & 63;
    int wid = (int)threadIdx.x >> 6;
    int s = tot;
#pragma unroll
    for (int off = 1; off < 64; off <<= 1) {
        int t = __shfl_up(s, off);
        if (lane >= off) s += t;
    }
    if (lane == 63) wsum[wid] = s;
    __syncthreads();
    int woff = 0;
#pragma unroll
    for (int w = 0; w < 4; ++w)
        if (w < wid) woff += wsum[w];
    int excl = woff + s - tot;
    v.x += excl; v.y += excl; v.z += excl; v.w += excl;
    if (base + 3 < n) {
        *(int4*)&partial[base] = v;
    } else {
        if (base + 0 < n) partial[base + 0] = v.x;
        if (base + 1 < n) partial[base + 1] = v.y;
        if (base + 2 < n) partial[base + 2] = v.z;
        if (base + 3 < n) partial[base + 3] = v.w;
    }
    if (threadIdx.x == 255) block_sums[blockIdx.x] = woff + s;
}

__global__ __launch_bounds__(256) void finalize_rowptr(const int* __restrict__ partial,
                                                       const int* __restrict__ block_sums,
                                                       int* __restrict__ row_ptr,
                                                       int n, int nblocks) {
    __shared__ int s_off;
    if (threadIdx.x < 64) {
        int lane = (int)threadIdx.x;
        int v = (lane < (int)blockIdx.x && lane < nblocks) ? block_sums[lane] : 0;
#pragma unroll
        for (int off = 32; off > 0; off >>= 1) v += __shfl_down(v, off);
        if (lane == 0) s_off = v;
    }
    __syncthreads();
    int off = s_off;
    int base = (int)blockIdx.x * 1024 + (int)threadIdx.x * 4;
#pragma unroll
    for (int q = 0; q < 4; ++q) {
        int i = base + q;
        if (i < n) row_ptr[i + 1] = partial[i] + off;
    }
    if (blockIdx.x == 0 && threadIdx.x == 0) row_ptr[0] = 0;
}

// Atomic-free scatter: slot = row_ptr[dst] + precomputed rank. Stores are
// fire-and-forget nt 8B (no latency chain), kernel runs at scatter-write BW.
__global__ __launch_bounds__(256) void fill_csr(
    const int* __restrict__ src, const int* __restrict__ dst,
    const float* __restrict__ w, const int* __restrict__ row_ptr,
    const int* __restrict__ rank, int2* __restrict__ csr_pack, int e) {
    int i = blockIdx.x * blockDim.x + threadIdx.x;
    if (i >= e) return;
    int d = dst[i];
    int p = row_ptr[d] + rank[i];
    unsigned long long v =
        ((unsigned long long)(unsigned)__float_as_uint(w[i]) << 32) | (unsigned)src[i];
    __builtin_nontemporal_store(v, (unsigned long long*)&csr_pack[p]);
}

// ---------------- Fused input/weight split-bf16 prep -------------------------

__global__ __launch_bounds__(256) void pack_all(
    const float* __restrict__ x, unsigned* __restrict__ xp, __half* __restrict__ xh, int nx,
    const float* __restrict__ w_rel0, const float* __restrict__ w_root0,
    const float* __restrict__ w_ro0, const float* __restrict__ w_rel1,
    const float* __restrict__ w_root1, const float* __restrict__ w_ro1,
    unsigned short* __restrict__ hi, unsigned short* __restrict__ lo) {
    int i = blockIdx.x * blockDim.x + threadIdx.x;
    if (i < nx) {
        float v = x[i];
        xp[i] = pack_split(v);
        xh[i] = __float2half(v);
    }
    if (i < 81920) {
        const float* src;
        int li;
        if (i < 8192) { src = w_rel0; li = i; }
        else if (i < 16384) { src = w_root0; li = i - 8192; }
        else if (i < 32768) { src = w_ro0; li = i - 16384; }
        else if (i < 49152) { src = w_rel1; li = i - 32768; }
        else if (i < 65536) { src = w_root1; li = i - 49152; }
        else { src = w_ro1; li = i - 65536; }
        unsigned p = pack_split(src[li]);
        hi[i] = (unsigned short)(p >> 16);
        lo[i] = (unsigned short)(p & 0xffffu);
    }
}

// ---------------- Aggregation: one wave per node, tiered unroll -------------

// fp16 gather, 1 channel per lane (2B loads), 128B per node row.
template <int T>
__device__ __forceinline__ void agg_tier64h(const __half* __restrict__ h,
                                            const int2* __restrict__ cp,
                                            int& e, int end, int lane, float& acc) {
    for (; e + T <= end; e += T) {
        int2 p[T];
        __half v[T];
#pragma unroll
        for (int q = 0; q < T; ++q) p[q] = cp[e + q];
#pragma unroll
        for (int q = 0; q < T; ++q) v[q] = h[p[q].x * 64 + lane];
#pragma unroll
        for (int q = 0; q < T; ++q) acc += __int_as_float(p[q].y) * __half2float(v[q]);
    }
}

// fp16 gather: one half2 (4B) per lane covers 2 channels; 256B per node row.
template <int T>
__device__ __forceinline__ void agg_tier128h(const unsigned* __restrict__ h2,
                                             const int2* __restrict__ cp,
                                             int& e, int end, int lane,
                                             float& ax, float& ay) {
    for (; e + T <= end; e += T) {
        int2 p[T];
        unsigned v[T];
#pragma unroll
        for (int q = 0; q < T; ++q) p[q] = cp[e + q];
#pragma unroll
        for (int q = 0; q < T; ++q) v[q] = h2[p[q].x * 64 + lane];
#pragma unroll
        for (int q = 0; q < T; ++q) {
            float wv = __int_as_float(p[q].y);
            float2 f = __half22float2(*(const __half2*)&v[q]);
            ax += wv * f.x;
            ay += wv * f.y;
        }
    }
}

// layer-0: fp16 gather of x (64 ch), packed split-bf16 out.
__global__ void aggregate64(const __half* __restrict__ h, const int* __restrict__ row_ptr,
                            const int2* __restrict__ csr_pack,
                            unsigned* __restrict__ agg, int n) {
    int lane = threadIdx.x & 63;
    int node = (int)((blockIdx.x * blockDim.x + threadIdx.x) >> 6);
    if (node >= n) return;
    node = __builtin_amdgcn_readfirstlane(node);
    int beg = row_ptr[node], end = row_ptr[node + 1];
    float inv = 1.0f / fmaxf((float)(end - beg), 1.0f);
    float acc = 0.0f;
    int e = beg;
    agg_tier64h<16>(h, csr_pack, e, end, lane, acc);
    agg_tier64h<8>(h, csr_pack, e, end, lane, acc);
    agg_tier64h<4>(h, csr_pack, e, end, lane, acc);
    agg_tier64h<1>(h, csr_pack, e, end, lane, acc);
    agg[node * 64 + lane] = pack_split(acc * inv);
}

// layer-1: fp16 gather of h2 (128 ch), packed split-bf16 out.
__global__ void aggregate128(const unsigned* __restrict__ h2h, const int* __restrict__ row_ptr,
                             const int2* __restrict__ csr_pack,
                             unsigned* __restrict__ agg, int n) {
    int lane = threadIdx.x & 63;
    int node = (int)((blockIdx.x * blockDim.x + threadIdx.x) >> 6);
    if (node >= n) return;
    node = __builtin_amdgcn_readfirstlane(node);
    int beg = row_ptr[node], end = row_ptr[node + 1];
    float inv = 1.0f / fmaxf((float)(end - beg), 1.0f);
    float ax = 0.0f, ay = 0.0f;
    int e = beg;
    agg_tier128h<16>(h2h, csr_pack, e, end, lane, ax, ay);
    agg_tier128h<8>(h2h, csr_pack, e, end, lane, ax, ay);
    agg_tier128h<4>(h2h, csr_pack, e, end, lane, ax, ay);
    agg_tier128h<1>(h2h, csr_pack, e, end, lane, ax, ay);
    uint2 o;
    o.x = pack_split(ax * inv);
    o.y = pack_split(ay * inv);
    ((uint2*)agg)[node * 64 + lane] = o;
}

// ---------------- MFMA split-bf16 GEMM, W held in registers ------------------
// EMIT: 0 = packed out; 1 = packed + fp16 out; 2 = fused prediction head.

template <int K, int NMAT, bool RELU, int EMIT>
__global__ __launch_bounds__(256, 2) void gemm_mfma(
    const unsigned* __restrict__ A0,
    const unsigned short* __restrict__ W0Hi, const unsigned short* __restrict__ W0Lo,
    const unsigned* __restrict__ A1,
    const unsigned short* __restrict__ W1Hi, const unsigned short* __restrict__ W1Lo,
    const float* __restrict__ bias, void* __restrict__ Yv, __half* __restrict__ Yh,
    const float* __restrict__ pred_w, const float* __restrict__ pred_b,
    float* __restrict__ pred_out, int n) {
    constexpr int KS = K / 32;
    const int lane = (int)threadIdx.x & 63;
    const int wv = (int)threadIdx.x >> 6;
    const int col = lane & 15;
    const int quad = lane >> 4;

    bf16x8 wh[NMAT][2][KS], wl[NMAT][2][KS];
#pragma unroll
    for (int m = 0; m < NMAT; ++m) {
        const unsigned short* Whi = m ? W1Hi : W0Hi;
        const unsigned short* Wlo = m ? W1Lo : W0Lo;
#pragma unroll
        for (int tt = 0; tt < 2; ++tt) {
            const int j = (2 * wv + tt) * 16 + col;
#pragma unroll
            for (int ks = 0; ks < KS; ++ks) {
                const size_t wo = (size_t)j * K + ks * 32 + quad * 8;
                wh[m][tt][ks] = *(const bf16x8*)&Whi[wo];
                wl[m][tt][ks] = *(const bf16x8*)&Wlo[wo];
            }
        }
    }

    float bb[2], wpv[2];
#pragma unroll
    for (int tt = 0; tt < 2; ++tt) {
        bb[tt] = bias[(2 * wv + tt) * 16 + col];
        if constexpr (EMIT == 2) wpv[tt] = pred_w[(2 * wv + tt) * 16 + col];
    }

    const int ngroups = (n + 15) >> 4;
    for (int g = (int)blockIdx.x; g < ngroups; g += (int)gridDim.x) {
        const int m0 = g * 16;
        int arow = m0 + col;
        if (arow >= n) arow = n - 1;

        f32x4 acc[2];
#pragma unroll
        for (int tt = 0; tt < 2; ++tt) acc[tt] = (f32x4){0.f, 0.f, 0.f, 0.f};

#pragma unroll
        for (int m = 0; m < NMAT; ++m) {
            const unsigned* Ap = m ? A1 : A0;
#pragma unroll
            for (int ks = 0; ks < KS; ++ks) {
                const unsigned* ap = &Ap[(size_t)arow * K + ks * 32 + quad * 8];
                uint4 q0 = *(const uint4*)ap;
                uint4 q1 = *(const uint4*)(ap + 4);
                bf16x8 ahi, alo;
                ahi[0] = (short)(q0.x >> 16); alo[0] = (short)(q0.x & 0xffffu);
                ahi[1] = (short)(q0.y >> 16); alo[1] = (short)(q0.y & 0xffffu);
                ahi[2] = (short)(q0.z >> 16); alo[2] = (short)(q0.z & 0xffffu);
                ahi[3] = (short)(q0.w >> 16); alo[3] = (short)(q0.w & 0xffffu);
                ahi[4] = (short)(q1.x >> 16); alo[4] = (short)(q1.x & 0xffffu);
                ahi[5] = (short)(q1.y >> 16); alo[5] = (short)(q1.y & 0xffffu);
                ahi[6] = (short)(q1.z >> 16); alo[6] = (short)(q1.z & 0xffffu);
                ahi[7] = (short)(q1.w >> 16); alo[7] = (short)(q1.w & 0xffffu);
#pragma unroll
                for (int tt = 0; tt < 2; ++tt) {
                    acc[tt] = __builtin_amdgcn_mfma_f32_16x16x32_bf16(ahi, wh[m][tt][ks], acc[tt], 0, 0, 0);
                    acc[tt] = __builtin_amdgcn_mfma_f32_16x16x32_bf16(ahi, wl[m][tt][ks], acc[tt], 0, 0, 0);
                    acc[tt] = __builtin_amdgcn_mfma_f32_16x16x32_bf16(alo, wh[m][tt][ks], acc[tt], 0, 0, 0);
                }
            }
        }

        float yv[2][4];
#pragma unroll
        for (int tt = 0; tt < 2; ++tt)
#pragma unroll
            for (int r = 0; r < 4; ++r) {
                float y = acc[tt][r] + bb[tt];
                if (RELU) y = fmaxf(y, 0.f);
                yv[tt][r] = y;
            }

        if constexpr (EMIT != 2) {
#pragma unroll
            for (int tt = 0; tt < 2; ++tt) {
                const int j = (2 * wv + tt) * 16 + col;
#pragma unroll
                for (int r = 0; r < 4; ++r) {
                    int node = m0 + quad * 4 + r;
                    if (node >= n) continue;
                    ((unsigned*)Yv)[(size_t)node * 128 + j] = pack_split(yv[tt][r]);
                    if constexpr (EMIT == 1)
                        Yh[(size_t)node * 128 + j] = __float2half(yv[tt][r]);
                }
            }
        } else {
            __shared__ float pp[4][16];
            float pr[4];
#pragma unroll
            for (int r = 0; r < 4; ++r) pr[r] = yv[0][r] * wpv[0] + yv[1][r] * wpv[1];
#pragma unroll
            for (int off = 8; off > 0; off >>= 1)
#pragma unroll
                for (int r = 0; r < 4; ++r) pr[r] += __shfl_down(pr[r], off);
            if (col == 0) {
#pragma unroll
                for (int r = 0; r < 4; ++r) pp[wv][quad * 4 + r] = pr[r];
            }
            __syncthreads();
            if (wv == 0 && lane < 16) {
                int node = m0 + lane;
                if (node < n)
                    pred_out[node] = pp[0][lane] + pp[1][lane] + pp[2][lane] + pp[3][lane] + pred_b[0];
            }
            __syncthreads();
        }
    }
}

// ---------------- Launch ----------------

extern "C" void kernel_launch(void* const* d_in, const int* in_sizes, int n_in,
                              void* d_out, int out_size, void* d_ws, size_t ws_size,
                              hipStream_t stream) {
    const float* x = (const float*)d_in[0];
    const int* edge_index = (const int*)d_in[1];
    const float* edge_w = (const float*)d_in[2];
    const float* W_rel0 = (const float*)d_in[3];
    const float* b_rel0 = (const float*)d_in[4];
    const float* W_root0 = (const float*)d_in[5];
    const float* W_ro0 = (const float*)d_in[6];
    const float* b_ro0 = (const float*)d_in[7];
    const float* W_rel1 = (const float*)d_in[8];
    const float* b_rel1 = (const float*)d_in[9];
    const float* W_root1 = (const float*)d_in[10];
    const float* W_ro1 = (const float*)d_in[11];
    const float* b_ro1 = (const float*)d_in[12];
    const float* W_prd = (const float*)d_in[13];
    const float* b_prd = (const float*)d_in[14];
    float* out = (float*)d_out;

    const int* e_src = edge_index;
    const int* e_dst = edge_index + N_EDGES;

    char* ws = (char*)d_ws;
    size_t off = 0;
    auto alloc = [&](size_t bytes) {
        char* p = ws + off;
        off += (bytes + 255) & ~(size_t)255;
        return p;
    };
    int* counts = (int*)alloc(N_NODES * 4);
    int* row_ptr = (int*)alloc((N_NODES + 1) * 4);
    int* partial = (int*)alloc(N_NODES * 4);
    int* block_sums = (int*)alloc(64 * 4);
    int* rank = (int*)alloc((size_t)N_EDGES * 4);
    int2* csr_pack = (int2*)alloc((size_t)N_EDGES * 8);
    unsigned short* WHI = (unsigned short*)alloc(81920 * 2);
    unsigned short* WLO = (unsigned short*)alloc(81920 * 2);
    unsigned* xp = (unsigned*)alloc((size_t)N_NODES * 64 * 4);
    __half* xh = (__half*)alloc((size_t)N_NODES * 64 * 2);
    unsigned* AGGp = (unsigned*)alloc((size_t)N_NODES * 128 * 4);
    unsigned* B1p = (unsigned*)alloc((size_t)N_NODES * 128 * 4);
    unsigned* B2p = (unsigned*)alloc((size_t)N_NODES * 128 * 4);
    __half* H2h = (__half*)alloc((size_t)N_NODES * 128 * 2);

    hipMemsetAsync(counts, 0, N_NODES * 4, stream);

    const int SB = (N_NODES + 1023) / 1024;
    count_edges<<<(N_EDGES / 4 + 255) / 256, 256, 0, stream>>>(e_dst, counts, rank, N_EDGES);
    scan_block<<<SB, 256, 0, stream>>>(counts, partial, block_sums, N_NODES);
    finalize_rowptr<<<SB, 256, 0, stream>>>(partial, block_sums, row_ptr, N_NODES, SB);
    fill_csr<<<(N_EDGES + 255) / 256, 256, 0, stream>>>(
        e_src, e_dst, edge_w, row_ptr, rank, csr_pack, N_EDGES);

    pack_all<<<(N_NODES * 64 + 255) / 256, 256, 0, stream>>>(
        x, xp, xh, N_NODES * 64, W_rel0, W_root0, W_ro0, W_rel1, W_root1, W_ro1, WHI, WLO);

    const int AGGB = (N_NODES * 64 + 255) / 256;  // wave per node
    const int GGRID = 512;                        // gemm blocks (grid-stride)

    // layer 0
    aggregate64<<<AGGB, 256, 0, stream>>>(xh, row_ptr, csr_pack, AGGp, N_NODES);
    gemm_mfma<64, 2, true, 0><<<GGRID, 256, 0, stream>>>(
        AGGp, WHI + 0, WLO + 0, xp, WHI + 8192, WLO + 8192, b_rel0,
        B1p, nullptr, nullptr, nullptr, nullptr, N_NODES);
    gemm_mfma<128, 1, true, 1><<<GGRID, 256, 0, stream>>>(
        B1p, WHI + 16384, WLO + 16384, nullptr, nullptr, nullptr, b_ro0,
        B2p, H2h, nullptr, nullptr, nullptr, N_NODES);
    // layer 1
    aggregate128<<<AGGB, 256, 0, stream>>>((const unsigned*)H2h, row_ptr, csr_pack, AGGp, N_NODES);
    gemm_mfma<128, 2, true, 0><<<GGRID, 256, 0, stream>>>(
        AGGp, WHI + 32768, WLO + 32768, B2p, WHI + 49152, WLO + 49152, b_rel1,
        B1p, nullptr, nullptr, nullptr, nullptr, N_NODES);
    // final layer + fused prediction head (h4 never materialized)
    gemm_mfma<128, 1, true, 2><<<GGRID, 256, 0, stream>>>(
        B1p, WHI + 65536, WLO + 65536, nullptr, nullptr, nullptr, b_ro1,
        nullptr, nullptr, W_prd, b_prd, out, N_NODES);
}

// Round 13
// 312.846 us; speedup vs baseline: 1.0642x; 1.0072x over previous
//
#include <hip/hip_runtime.h>
#include <hip/hip_fp16.h>

#define N_NODES 50000
#define N_EDGES 800000
#define IN_CH 64
#define HID 128

typedef __attribute__((ext_vector_type(8))) short bf16x8;
typedef __attribute__((ext_vector_type(4))) float f32x4;

// Split-bf16 packing: v ~= hi + lo, both bf16 (RNE). Packed as (hi<<16)|lo.
__device__ __forceinline__ unsigned pack_split(float v) {
    unsigned u = __float_as_uint(v);
    unsigned hi = (u + 0x7fffu + ((u >> 16) & 1u)) & 0xffff0000u;
    float r = v - __uint_as_float(hi);
    unsigned ur = __float_as_uint(r);
    unsigned lo = ((ur + 0x7fffu + ((ur >> 16) & 1u)) >> 16) & 0xffffu;
    return hi | lo;
}

__device__ __forceinline__ float unpack_f(unsigned u) {
    return __uint_as_float(u & 0xffff0000u) + __uint_as_float(u << 16);
}

// ---------------- Fused count+rank+pack ----------------
// Edge part (first e/4 threads): rank[i] = fetch-add counts[dst[i]] (the
// within-segment slot used by the atomic-free fill). Pack part (all threads):
// x -> split-bf16 + fp16; first 81920 also pack one weight element.
// Atomic-latency-bound and BW-bound work overlap in one dispatch.

__global__ __launch_bounds__(256) void count_pack(
    const int* __restrict__ dst, int* __restrict__ counts, int* __restrict__ rank, int e,
    const float* __restrict__ x, unsigned* __restrict__ xp, __half* __restrict__ xh, int nx,
    const float* __restrict__ w_rel0, const float* __restrict__ w_root0,
    const float* __restrict__ w_ro0, const float* __restrict__ w_rel1,
    const float* __restrict__ w_root1, const float* __restrict__ w_ro1,
    unsigned short* __restrict__ hi, unsigned short* __restrict__ lo) {
    int tid = blockIdx.x * blockDim.x + threadIdx.x;
    int i4 = tid * 4;
    if (i4 + 3 < e) {
        int4 d = *(const int4*)&dst[i4];
        int4 r;
        r.x = atomicAdd(&counts[d.x], 1);
        r.y = atomicAdd(&counts[d.y], 1);
        r.z = atomicAdd(&counts[d.z], 1);
        r.w = atomicAdd(&counts[d.w], 1);
        *(int4*)&rank[i4] = r;
    } else if (i4 < e) {
        for (int i = i4; i < e; ++i) rank[i] = atomicAdd(&counts[dst[i]], 1);
    }
    if (tid < nx) {
        float v = x[tid];
        xp[tid] = pack_split(v);
        xh[tid] = __float2half(v);
    }
    if (tid < 81920) {
        const float* src;
        int li;
        if (tid < 8192) { src = w_rel0; li = tid; }
        else if (tid < 16384) { src = w_root0; li = tid - 8192; }
        else if (tid < 32768) { src = w_ro0; li = tid - 16384; }
        else if (tid < 49152) { src = w_rel1; li = tid - 32768; }
        else if (tid < 65536) { src = w_root1; li = tid - 49152; }
        else { src = w_ro1; li = tid - 65536; }
        unsigned p = pack_split(src[li]);
        hi[tid] = (unsigned short)(p >> 16);
        lo[tid] = (unsigned short)(p & 0xffffu);
    }
}

__global__ __launch_bounds__(256) void scan_block(const int* __restrict__ counts,
                                                  int* __restrict__ partial,
                                                  int* __restrict__ block_sums, int n) {
    __shared__ int wsum[4];
    int base = (int)blockIdx.x * 1024 + (int)threadIdx.x * 4;
    int4 v = make_int4(0, 0, 0, 0);
    if (base + 3 < n) {
        v = *(const int4*)&counts[base];
    } else {
        if (base + 0 < n) v.x = counts[base + 0];
        if (base + 1 < n) v.y = counts[base + 1];
        if (base + 2 < n) v.z = counts[base + 2];
        if (base + 3 < n) v.w = counts[base + 3];
    }
    v.y += v.x; v.z += v.y; v.w += v.z;
    int tot = v.w;
    int lane = (int)threadIdx.x & 63;
    int wid = (int)threadIdx.x >> 6;
    int s = tot;
#pragma unroll
    for (int off = 1; off < 64; off <<= 1) {
        int t = __shfl_up(s, off);
        if (lane >= off) s += t;
    }
    if (lane == 63) wsum[wid] = s;
    __syncthreads();
    int woff = 0;
#pragma unroll
    for (int w = 0; w < 4; ++w)
        if (w < wid) woff += wsum[w];
    int excl = woff + s - tot;
    v.x += excl; v.y += excl; v.z += excl; v.w += excl;
    if (base + 3 < n) {
        *(int4*)&partial[base] = v;
    } else {
        if (base + 0 < n) partial[base + 0] = v.x;
        if (base + 1 < n) partial[base + 1] = v.y;
        if (base + 2 < n) partial[base + 2] = v.z;
        if (base + 3 < n) partial[base + 3] = v.w;
    }
    if (threadIdx.x == 255) block_sums[blockIdx.x] = woff + s;
}

__global__ __launch_bounds__(256) void finalize_rowptr(const int* __restrict__ partial,
                                                       const int* __restrict__ block_sums,
                                                       int* __restrict__ row_ptr,
                                                       int n, int nblocks) {
    __shared__ int s_off;
    if (threadIdx.x < 64) {
        int lane = (int)threadIdx.x;
        int v = (lane < (int)blockIdx.x && lane < nblocks) ? block_sums[lane] : 0;
#pragma unroll
        for (int off = 32; off > 0; off >>= 1) v += __shfl_down(v, off);
        if (lane == 0) s_off = v;
    }
    __syncthreads();
    int off = s_off;
    int base = (int)blockIdx.x * 1024 + (int)threadIdx.x * 4;
#pragma unroll
    for (int q = 0; q < 4; ++q) {
        int i = base + q;
        if (i < n) row_ptr[i + 1] = partial[i] + off;
    }
    if (blockIdx.x == 0 && threadIdx.x == 0) row_ptr[0] = 0;
}

// Atomic-free vectorized scatter: 4 edges/thread, nt 8B stores fire-and-forget.
__global__ __launch_bounds__(256) void fill_csr(
    const int* __restrict__ src, const int* __restrict__ dst,
    const float* __restrict__ w, const int* __restrict__ row_ptr,
    const int* __restrict__ rank, int2* __restrict__ csr_pack, int e) {
    int i4 = (blockIdx.x * blockDim.x + threadIdx.x) * 4;
    if (i4 + 3 < e) {
        int4 d = *(const int4*)&dst[i4];
        int4 r = *(const int4*)&rank[i4];
        int4 s = *(const int4*)&src[i4];
        float4 wv = *(const float4*)&w[i4];
        int p0 = row_ptr[d.x] + r.x;
        int p1 = row_ptr[d.y] + r.y;
        int p2 = row_ptr[d.z] + r.z;
        int p3 = row_ptr[d.w] + r.w;
        __builtin_nontemporal_store(
            ((unsigned long long)(unsigned)__float_as_uint(wv.x) << 32) | (unsigned)s.x,
            (unsigned long long*)&csr_pack[p0]);
        __builtin_nontemporal_store(
            ((unsigned long long)(unsigned)__float_as_uint(wv.y) << 32) | (unsigned)s.y,
            (unsigned long long*)&csr_pack[p1]);
        __builtin_nontemporal_store(
            ((unsigned long long)(unsigned)__float_as_uint(wv.z) << 32) | (unsigned)s.z,
            (unsigned long long*)&csr_pack[p2]);
        __builtin_nontemporal_store(
            ((unsigned long long)(unsigned)__float_as_uint(wv.w) << 32) | (unsigned)s.w,
            (unsigned long long*)&csr_pack[p3]);
    } else {
        for (int i = i4; i < e; ++i) {
            int d = dst[i];
            int p = row_ptr[d] + rank[i];
            unsigned long long v =
                ((unsigned long long)(unsigned)__float_as_uint(w[i]) << 32) | (unsigned)src[i];
            __builtin_nontemporal_store(v, (unsigned long long*)&csr_pack[p]);
        }
    }
}

// ---------------- Aggregation ----------------
// Generic tier: half2 gather with ROW_STRIDE half2s per node row.

template <int T, int ROW_STRIDE>
__device__ __forceinline__ void agg_tier_h2(const __half2* __restrict__ h2,
                                            const int2* __restrict__ cp,
                                            int& e, int end, int sl,
                                            float& ax, float& ay) {
    for (; e + T <= end; e += T) {
        int2 p[T];
        __half2 v[T];
#pragma unroll
        for (int q = 0; q < T; ++q) p[q] = cp[e + q];
#pragma unroll
        for (int q = 0; q < T; ++q) v[q] = h2[(size_t)p[q].x * ROW_STRIDE + sl];
#pragma unroll
        for (int q = 0; q < T; ++q) {
            float wv = __int_as_float(p[q].y);
            float2 f = __half22float2(v[q]);
            ax += wv * f.x;
            ay += wv * f.y;
        }
    }
}

// layer-0: fp16 gather of x (64 ch = 32 half2 = 128B row). TWO nodes per wave
// (32 lanes each) -> 2 rows of gathers in flight, half the loop iterations.
__global__ void aggregate64(const __half2* __restrict__ xh2, const int* __restrict__ row_ptr,
                            const int2* __restrict__ csr_pack,
                            unsigned* __restrict__ agg, int n) {
    int tid = blockIdx.x * blockDim.x + threadIdx.x;
    int lane = tid & 63;
    int half = lane >> 5;
    int sl = lane & 31;  // half2 index: channels 2*sl, 2*sl+1
    int node = ((tid >> 6) << 1) + half;
    if (node >= n) return;
    int beg = row_ptr[node], end = row_ptr[node + 1];
    float inv = 1.0f / fmaxf((float)(end - beg), 1.0f);
    float ax = 0.0f, ay = 0.0f;
    int e = beg;
    agg_tier_h2<16, 32>(xh2, csr_pack, e, end, sl, ax, ay);
    agg_tier_h2<8, 32>(xh2, csr_pack, e, end, sl, ax, ay);
    agg_tier_h2<4, 32>(xh2, csr_pack, e, end, sl, ax, ay);
    agg_tier_h2<1, 32>(xh2, csr_pack, e, end, sl, ax, ay);
    uint2 o;
    o.x = pack_split(ax * inv);
    o.y = pack_split(ay * inv);
    ((uint2*)agg)[(size_t)node * 32 + sl] = o;  // channels 2sl,2sl+1
}

// layer-1: fp16 gather of h2 (128 ch = 64 half2 = 256B row), one wave/node.
__global__ void aggregate128(const __half2* __restrict__ h2h, const int* __restrict__ row_ptr,
                             const int2* __restrict__ csr_pack,
                             unsigned* __restrict__ agg, int n) {
    int lane = threadIdx.x & 63;
    int node = (int)((blockIdx.x * blockDim.x + threadIdx.x) >> 6);
    if (node >= n) return;
    node = __builtin_amdgcn_readfirstlane(node);
    int beg = row_ptr[node], end = row_ptr[node + 1];
    float inv = 1.0f / fmaxf((float)(end - beg), 1.0f);
    float ax = 0.0f, ay = 0.0f;
    int e = beg;
    agg_tier_h2<16, 64>(h2h, csr_pack, e, end, lane, ax, ay);
    agg_tier_h2<8, 64>(h2h, csr_pack, e, end, lane, ax, ay);
    agg_tier_h2<4, 64>(h2h, csr_pack, e, end, lane, ax, ay);
    agg_tier_h2<1, 64>(h2h, csr_pack, e, end, lane, ax, ay);
    uint2 o;
    o.x = pack_split(ax * inv);
    o.y = pack_split(ay * inv);
    ((uint2*)agg)[(size_t)node * 64 + lane] = o;
}

// ---------------- MFMA split-bf16 GEMM, W held in registers ------------------
// EMIT: 0 = packed out; 1 = packed + fp16 out; 2 = fused prediction head.

template <int K, int NMAT, bool RELU, int EMIT>
__global__ __launch_bounds__(256, 2) void gemm_mfma(
    const unsigned* __restrict__ A0,
    const unsigned short* __restrict__ W0Hi, const unsigned short* __restrict__ W0Lo,
    const unsigned* __restrict__ A1,
    const unsigned short* __restrict__ W1Hi, const unsigned short* __restrict__ W1Lo,
    const float* __restrict__ bias, void* __restrict__ Yv, __half* __restrict__ Yh,
    const float* __restrict__ pred_w, const float* __restrict__ pred_b,
    float* __restrict__ pred_out, int n) {
    constexpr int KS = K / 32;
    const int lane = (int)threadIdx.x & 63;
    const int wv = (int)threadIdx.x >> 6;
    const int col = lane & 15;
    const int quad = lane >> 4;

    bf16x8 wh[NMAT][2][KS], wl[NMAT][2][KS];
#pragma unroll
    for (int m = 0; m < NMAT; ++m) {
        const unsigned short* Whi = m ? W1Hi : W0Hi;
        const unsigned short* Wlo = m ? W1Lo : W0Lo;
#pragma unroll
        for (int tt = 0; tt < 2; ++tt) {
            const int j = (2 * wv + tt) * 16 + col;
#pragma unroll
            for (int ks = 0; ks < KS; ++ks) {
                const size_t wo = (size_t)j * K + ks * 32 + quad * 8;
                wh[m][tt][ks] = *(const bf16x8*)&Whi[wo];
                wl[m][tt][ks] = *(const bf16x8*)&Wlo[wo];
            }
        }
    }

    float bb[2], wpv[2];
#pragma unroll
    for (int tt = 0; tt < 2; ++tt) {
        bb[tt] = bias[(2 * wv + tt) * 16 + col];
        if constexpr (EMIT == 2) wpv[tt] = pred_w[(2 * wv + tt) * 16 + col];
    }

    const int ngroups = (n + 15) >> 4;
    for (int g = (int)blockIdx.x; g < ngroups; g += (int)gridDim.x) {
        const int m0 = g * 16;
        int arow = m0 + col;
        if (arow >= n) arow = n - 1;

        f32x4 acc[2];
#pragma unroll
        for (int tt = 0; tt < 2; ++tt) acc[tt] = (f32x4){0.f, 0.f, 0.f, 0.f};

#pragma unroll
        for (int m = 0; m < NMAT; ++m) {
            const unsigned* Ap = m ? A1 : A0;
#pragma unroll
            for (int ks = 0; ks < KS; ++ks) {
                const unsigned* ap = &Ap[(size_t)arow * K + ks * 32 + quad * 8];
                uint4 q0 = *(const uint4*)ap;
                uint4 q1 = *(const uint4*)(ap + 4);
                bf16x8 ahi, alo;
                ahi[0] = (short)(q0.x >> 16); alo[0] = (short)(q0.x & 0xffffu);
                ahi[1] = (short)(q0.y >> 16); alo[1] = (short)(q0.y & 0xffffu);
                ahi[2] = (short)(q0.z >> 16); alo[2] = (short)(q0.z & 0xffffu);
                ahi[3] = (short)(q0.w >> 16); alo[3] = (short)(q0.w & 0xffffu);
                ahi[4] = (short)(q1.x >> 16); alo[4] = (short)(q1.x & 0xffffu);
                ahi[5] = (short)(q1.y >> 16); alo[5] = (short)(q1.y & 0xffffu);
                ahi[6] = (short)(q1.z >> 16); alo[6] = (short)(q1.z & 0xffffu);
                ahi[7] = (short)(q1.w >> 16); alo[7] = (short)(q1.w & 0xffffu);
#pragma unroll
                for (int tt = 0; tt < 2; ++tt) {
                    acc[tt] = __builtin_amdgcn_mfma_f32_16x16x32_bf16(ahi, wh[m][tt][ks], acc[tt], 0, 0, 0);
                    acc[tt] = __builtin_amdgcn_mfma_f32_16x16x32_bf16(ahi, wl[m][tt][ks], acc[tt], 0, 0, 0);
                    acc[tt] = __builtin_amdgcn_mfma_f32_16x16x32_bf16(alo, wh[m][tt][ks], acc[tt], 0, 0, 0);
                }
            }
        }

        float yv[2][4];
#pragma unroll
        for (int tt = 0; tt < 2; ++tt)
#pragma unroll
            for (int r = 0; r < 4; ++r) {
                float y = acc[tt][r] + bb[tt];
                if (RELU) y = fmaxf(y, 0.f);
                yv[tt][r] = y;
            }

        if constexpr (EMIT != 2) {
#pragma unroll
            for (int tt = 0; tt < 2; ++tt) {
                const int j = (2 * wv + tt) * 16 + col;
#pragma unroll
                for (int r = 0; r < 4; ++r) {
                    int node = m0 + quad * 4 + r;
                    if (node >= n) continue;
                    ((unsigned*)Yv)[(size_t)node * 128 + j] = pack_split(yv[tt][r]);
                    if constexpr (EMIT == 1)
                        Yh[(size_t)node * 128 + j] = __float2half(yv[tt][r]);
                }
            }
        } else {
            __shared__ float pp[4][16];
            float pr[4];
#pragma unroll
            for (int r = 0; r < 4; ++r) pr[r] = yv[0][r] * wpv[0] + yv[1][r] * wpv[1];
#pragma unroll
            for (int off = 8; off > 0; off >>= 1)
#pragma unroll
                for (int r = 0; r < 4; ++r) pr[r] += __shfl_down(pr[r], off);
            if (col == 0) {
#pragma unroll
                for (int r = 0; r < 4; ++r) pp[wv][quad * 4 + r] = pr[r];
            }
            __syncthreads();
            if (wv == 0 && lane < 16) {
                int node = m0 + lane;
                if (node < n)
                    pred_out[node] = pp[0][lane] + pp[1][lane] + pp[2][lane] + pp[3][lane] + pred_b[0];
            }
            __syncthreads();
        }
    }
}

// ---------------- Launch ----------------

extern "C" void kernel_launch(void* const* d_in, const int* in_sizes, int n_in,
                              void* d_out, int out_size, void* d_ws, size_t ws_size,
                              hipStream_t stream) {
    const float* x = (const float*)d_in[0];
    const int* edge_index = (const int*)d_in[1];
    const float* edge_w = (const float*)d_in[2];
    const float* W_rel0 = (const float*)d_in[3];
    const float* b_rel0 = (const float*)d_in[4];
    const float* W_root0 = (const float*)d_in[5];
    const float* W_ro0 = (const float*)d_in[6];
    const float* b_ro0 = (const float*)d_in[7];
    const float* W_rel1 = (const float*)d_in[8];
    const float* b_rel1 = (const float*)d_in[9];
    const float* W_root1 = (const float*)d_in[10];
    const float* W_ro1 = (const float*)d_in[11];
    const float* b_ro1 = (const float*)d_in[12];
    const float* W_prd = (const float*)d_in[13];
    const float* b_prd = (const float*)d_in[14];
    float* out = (float*)d_out;

    const int* e_src = edge_index;
    const int* e_dst = edge_index + N_EDGES;

    char* ws = (char*)d_ws;
    size_t off = 0;
    auto alloc = [&](size_t bytes) {
        char* p = ws + off;
        off += (bytes + 255) & ~(size_t)255;
        return p;
    };
    int* counts = (int*)alloc(N_NODES * 4);
    int* row_ptr = (int*)alloc((N_NODES + 1) * 4);
    int* partial = (int*)alloc(N_NODES * 4);
    int* block_sums = (int*)alloc(64 * 4);
    int* rank = (int*)alloc((size_t)N_EDGES * 4);
    int2* csr_pack = (int2*)alloc((size_t)N_EDGES * 8);
    unsigned short* WHI = (unsigned short*)alloc(81920 * 2);
    unsigned short* WLO = (unsigned short*)alloc(81920 * 2);
    unsigned* xp = (unsigned*)alloc((size_t)N_NODES * 64 * 4);
    __half* xh = (__half*)alloc((size_t)N_NODES * 64 * 2);
    unsigned* AGGp = (unsigned*)alloc((size_t)N_NODES * 128 * 4);
    unsigned* B1p = (unsigned*)alloc((size_t)N_NODES * 128 * 4);
    unsigned* B2p = (unsigned*)alloc((size_t)N_NODES * 128 * 4);
    __half* H2h = (__half*)alloc((size_t)N_NODES * 128 * 2);

    hipMemsetAsync(counts, 0, N_NODES * 4, stream);

    const int SB = (N_NODES + 1023) / 1024;
    const int NX = N_NODES * 64;
    // grid must cover both pack (NX threads) and edges (N_EDGES/4 threads)
    count_pack<<<(NX + 255) / 256, 256, 0, stream>>>(
        e_dst, counts, rank, N_EDGES,
        x, xp, xh, NX, W_rel0, W_root0, W_ro0, W_rel1, W_root1, W_ro1, WHI, WLO);
    scan_block<<<SB, 256, 0, stream>>>(counts, partial, block_sums, N_NODES);
    finalize_rowptr<<<SB, 256, 0, stream>>>(partial, block_sums, row_ptr, N_NODES, SB);
    fill_csr<<<(N_EDGES / 4 + 255) / 256, 256, 0, stream>>>(
        e_src, e_dst, edge_w, row_ptr, rank, csr_pack, N_EDGES);

    const int AGGB64 = (((N_NODES + 1) / 2) * 64 + 255) / 256;  // 2 nodes/wave
    const int AGGB = (N_NODES * 64 + 255) / 256;                // 1 node/wave
    const int GGRID = 512;

    // layer 0
    aggregate64<<<AGGB64, 256, 0, stream>>>((const __half2*)xh, row_ptr, csr_pack, AGGp, N_NODES);
    gemm_mfma<64, 2, true, 0><<<GGRID, 256, 0, stream>>>(
        AGGp, WHI + 0, WLO + 0, xp, WHI + 8192, WLO + 8192, b_rel0,
        B1p, nullptr, nullptr, nullptr, nullptr, N_NODES);
    gemm_mfma<128, 1, true, 1><<<GGRID, 256, 0, stream>>>(
        B1p, WHI + 16384, WLO + 16384, nullptr, nullptr, nullptr, b_ro0,
        B2p, H2h, nullptr, nullptr, nullptr, N_NODES);
    // layer 1
    aggregate128<<<AGGB, 256, 0, stream>>>((const __half2*)H2h, row_ptr, csr_pack, AGGp, N_NODES);
    gemm_mfma<128, 2, true, 0><<<GGRID, 256, 0, stream>>>(
        AGGp, WHI + 32768, WLO + 32768, B2p, WHI + 49152, WLO + 49152, b_rel1,
        B1p, nullptr, nullptr, nullptr, nullptr, N_NODES);
    // final layer + fused prediction head (h4 never materialized)
    gemm_mfma<128, 1, true, 2><<<GGRID, 256, 0, stream>>>(
        B1p, WHI + 65536, WLO + 65536, nullptr, nullptr, nullptr, b_ro1,
        nullptr, nullptr, W_prd, b_prd, out, N_NODES);
}